// Round 5
// baseline (153.633 us; speedup 1.0000x reference)
//
#include <hip/hip_runtime.h>
#include <hip/hip_bf16.h>
#include <math.h>

// N=1e6 points, M=1e5 segments, D=64, K=32. pt_inv SORTED.
// Scan kernel: wave = 64 contiguous rows, staged via global_load_lds DMA
// (8 stages x 8 rows, ring-2 LDS buffers, counted vmcnt(4) waits).
// Consume lane=col from LDS; run flushes buffered in LDS (lgkm domain) and
// drained once at wave end so stores never pollute the vmcnt pipeline counts.

#define D_IN 64
#define K_OUT 32
#define WPB 4
#define RW 64              // rows per wave
#define QMAX 16            // buffered runs per wave (overflow ~1e-4 of waves)
#define ENC_NEG_INF 0x007FFFFFu

typedef __attribute__((address_space(3))) uint32_t lds_u32_t;
typedef __attribute__((address_space(1))) uint32_t glb_u32_t;

__device__ __forceinline__ unsigned enc_f32(float f) {
    unsigned u = __float_as_uint(f);
    return (u & 0x80000000u) ? ~u : (u | 0x80000000u);
}
__device__ __forceinline__ float dec_f32(unsigned u) {
    unsigned b = (u & 0x80000000u) ? (u ^ 0x80000000u) : ~u;
    return __uint_as_float(b);
}

__device__ __forceinline__ void dma16(const float* gsrc, float* ldst) {
    // async global->LDS, 16B/lane; dest = uniform base + lane*16 (HW rule)
    __builtin_amdgcn_global_load_lds((const glb_u32_t*)gsrc, (lds_u32_t*)ldst, 16, 0, 0);
}

__global__ __launch_bounds__(256) void init_pooled_kernel(uint4* __restrict__ p, int n4)
{
    const uint4 v = make_uint4(ENC_NEG_INF, ENC_NEG_INF, ENC_NEG_INF, ENC_NEG_INF);
    for (int i = blockIdx.x * blockDim.x + threadIdx.x; i < n4; i += gridDim.x * blockDim.x)
        p[i] = v;
}

__device__ __noinline__ void drain_runs(
    float (*obv)[64], int* obs, unsigned* __restrict__ pooled,
    int lane, int nq, int runBase, int isFinal)
{
    for (int q = 0; q < nq; ++q) {
        const float v  = obv[q][lane];
        const int   sg = obs[q];                    // broadcast read
        const int   runId = runBase + q;
        const bool  at = (runId == 0) || (isFinal && (q == nq - 1));
        unsigned* p = pooled + (size_t)sg * D_IN + lane;
        const unsigned e = enc_f32(v);
        if (at) atomicMax(p, e);
        else    *p = e;                              // interior run: single writer
    }
}

__global__ __launch_bounds__(256) void scan_dma_kernel(
    const int*   __restrict__ ind_arr,
    const float* __restrict__ g,
    const float* __restrict__ l,
    const int*   __restrict__ seg_arr,
    unsigned*    __restrict__ pooled,
    int n)   // requires n % 64 == 0
{
    __shared__ __align__(16) float pipe[WPB][2][2][512]; // [wave][buf][g/l][8rows*64] = 32KB
    __shared__ __align__(16) float obv[WPB][QMAX][64];   // 16KB run buffer
    __shared__ int obs[WPB][QMAX];

    const int tid  = threadIdx.x;
    const int wid  = tid >> 6;
    const int lane = tid & 63;
    const int gw   = blockIdx.x * WPB + wid;
    const int wbase = gw * RW;
    if (wbase >= n) return;

    // meta: idx[k] = ind[wbase + 4k + (lane>>4)] (per-lane row index for DMA src)
    int idx[16];
    #pragma unroll
    for (int k = 0; k < 16; ++k)
        idx[k] = ind_arr[wbase + 4 * k + (lane >> 4)];
    const int segv = seg_arr[wbase + lane];

    float m   = -INFINITY;
    int   cur = __shfl(segv, 0);
    int   nq = 0, runBase = 0;

    const int cg4 = (lane & 15) << 2;   // float offset within a g row
    const int l4  = lane << 2;          // float offset within a 4-row l block

#define WAITV4 asm volatile("s_waitcnt vmcnt(4)" ::: "memory")
#define WAITV0 asm volatile("s_waitcnt vmcnt(0)" ::: "memory")
#define LGKM0  asm volatile("s_waitcnt lgkmcnt(0)" ::: "memory")

#define ISSUE(s) do {                                                          \
    float* bg_ = &pipe[wid][(s) & 1][0][0];                                    \
    float* bl_ = &pipe[wid][(s) & 1][1][0];                                    \
    dma16(g + (size_t)idx[2*(s)    ] * D_IN + cg4, bg_);                       \
    dma16(g + (size_t)idx[2*(s) + 1] * D_IN + cg4, bg_ + 256);                 \
    dma16(l + ((size_t)wbase + 8*(s)    ) * D_IN + l4, bl_);                   \
    dma16(l + ((size_t)wbase + 8*(s) + 4) * D_IN + l4, bl_ + 256);             \
} while (0)

    auto FLUSH = [&]() {
        if (nq == QMAX) {                 // rare overflow: drain + resync vmcnt
            LGKM0;
            drain_runs(&obv[wid][0], &obs[wid][0], pooled, lane, nq, runBase, 0);
            runBase += nq; nq = 0;
            WAITV0;                       // restore pipeline count sanity
        }
        obv[wid][nq][lane] = m;
        if (lane == 0) obs[wid][nq] = cur;
        ++nq;
    };

#define ROWSTEP(s, j) do {                                                     \
    const float x_ = pipe[wid][(s)&1][0][(j)*64 + lane]                        \
                   + pipe[wid][(s)&1][1][(j)*64 + lane];                       \
    const int sr_ = __shfl(segv, (s)*8 + (j));                                 \
    if (sr_ != cur) { FLUSH(); cur = sr_; m = x_; }                            \
    else            { m = fmaxf(m, x_); }                                      \
} while (0)

#define CONS(s) do { ROWSTEP(s,0); ROWSTEP(s,1); ROWSTEP(s,2); ROWSTEP(s,3);   \
                     ROWSTEP(s,4); ROWSTEP(s,5); ROWSTEP(s,6); ROWSTEP(s,7); } while (0)

    ISSUE(0); ISSUE(1);
    WAITV4;  CONS(0); LGKM0; ISSUE(2);
    WAITV4;  CONS(1); LGKM0; ISSUE(3);
    WAITV4;  CONS(2); LGKM0; ISSUE(4);
    WAITV4;  CONS(3); LGKM0; ISSUE(5);
    WAITV4;  CONS(4); LGKM0; ISSUE(6);
    WAITV4;  CONS(5); LGKM0; ISSUE(7);
    WAITV4;  CONS(6);
    WAITV0;  CONS(7);
    FLUSH();                               // final run
    LGKM0;
    drain_runs(&obv[wid][0], &obs[wid][0], pooled, lane, nq, runBase, 1);

#undef ISSUE
#undef ROWSTEP
#undef CONS
#undef WAITV4
#undef WAITV0
#undef LGKM0
}

// Decode + (pooled @ W + b) -> relu. One wave per 2 segments.
__global__ __launch_bounds__(256) void gemm_kernel(
    const unsigned* __restrict__ pooled, const float* __restrict__ W,
    const float* __restrict__ b, float* __restrict__ out, int M)
{
    __shared__ float Ws[D_IN * K_OUT];
    __shared__ float bs[K_OUT];
    __shared__ float pool[WPB][2 * D_IN];

    const int tid = threadIdx.x;
    for (int i = tid; i < D_IN * K_OUT; i += 256) Ws[i] = W[i];
    if (tid < K_OUT) bs[tid] = b[tid];

    const int wid  = tid >> 6;
    const int lane = tid & 63;
    const int s0   = (blockIdx.x * WPB + wid) * 2;

    if (s0 < M) {
        const int nvals = min(2, M - s0) * D_IN;
        uint2 u = make_uint2(ENC_NEG_INF, ENC_NEG_INF);
        if (lane * 2 < nvals)
            u = *reinterpret_cast<const uint2*>(pooled + (size_t)s0 * D_IN + lane * 2);
        pool[wid][lane * 2 + 0] = (u.x == ENC_NEG_INF) ? 0.0f : dec_f32(u.x);
        pool[wid][lane * 2 + 1] = (u.y == ENC_NEG_INF) ? 0.0f : dec_f32(u.y);
    }
    __syncthreads();

    const int h = lane >> 5;
    const int k = lane & 31;
    const int s = s0 + h;
    if (s0 < M && s < M) {
        float acc = bs[k];
        const float* pr = &pool[wid][h * D_IN];
        #pragma unroll
        for (int c = 0; c < D_IN; ++c)
            acc = fmaf(pr[c], Ws[c * K_OUT + k], acc);
        out[(size_t)s * K_OUT + k] = fmaxf(acc, 0.0f);
    }
}

// ---------- Fallback path (ws too small or N%64!=0): round-1 design ----------
__global__ __launch_bounds__(256) void seg_starts_kernel(
    const int* __restrict__ pt_inv, int n, int* __restrict__ starts, int M)
{
    int s = blockIdx.x * blockDim.x + threadIdx.x;
    if (s > M) return;
    int lo = 0, hi = n;
    while (lo < hi) { int mid = (lo + hi) >> 1; if (pt_inv[mid] < s) lo = mid + 1; else hi = mid; }
    starts[s] = lo;
}

__global__ __launch_bounds__(256) void pool_gemm_kernel(
    const int* __restrict__ shuffled_ind, const float* __restrict__ g,
    const float* __restrict__ l, const int* __restrict__ starts,
    const float* __restrict__ W, const float* __restrict__ b,
    float* __restrict__ out, int M)
{
    __shared__ float Ws[D_IN * K_OUT];
    __shared__ float bs[K_OUT];
    __shared__ float pool[WPB][D_IN];
    const int tid = threadIdx.x;
    for (int i = tid; i < D_IN * K_OUT; i += 256) Ws[i] = W[i];
    if (tid < K_OUT) bs[tid] = b[tid];
    const int wid = tid >> 6, lane = tid & 63;
    const int s = blockIdx.x * WPB + wid;
    const bool active = (s < M);
    float m = -INFINITY;
    if (active) {
        const int p0 = starts[s], p1 = starts[s + 1];
        for (int p = p0; p < p1; ++p) {
            const int ind = shuffled_ind[p];
            m = fmaxf(m, g[(size_t)ind * D_IN + lane] + l[(size_t)p * D_IN + lane]);
        }
        if (p1 <= p0) m = 0.0f;
    }
    if (active) pool[wid][lane] = m;
    __syncthreads();
    if (active && lane < K_OUT) {
        float acc = bs[lane];
        #pragma unroll
        for (int c = 0; c < D_IN; ++c) acc = fmaf(pool[wid][c], Ws[c * K_OUT + lane], acc);
        out[(size_t)s * K_OUT + lane] = fmaxf(acc, 0.0f);
    }
}

extern "C" void kernel_launch(void* const* d_in, const int* in_sizes, int n_in,
                              void* d_out, int out_size, void* d_ws, size_t ws_size,
                              hipStream_t stream)
{
    const int*   shuffled_ind = (const int*)  d_in[0];
    const float* g            = (const float*)d_in[1];
    const float* l            = (const float*)d_in[2];
    const int*   pt_inv       = (const int*)  d_in[3];
    const float* W            = (const float*)d_in[4];
    const float* b            = (const float*)d_in[5];
    float*       out          = (float*)d_out;

    const int N = in_sizes[0];
    const int M = out_size / K_OUT;

    const size_t pooled_bytes = (size_t)M * D_IN * sizeof(unsigned);

    if (ws_size >= pooled_bytes && (N % RW) == 0 && N >= RW) {
        unsigned* pooled = (unsigned*)d_ws;
        {
            const int n4 = (int)(pooled_bytes / 16);
            init_pooled_kernel<<<512, 256, 0, stream>>>((uint4*)pooled, n4);
        }
        {
            const int waves  = N / RW;
            const int blocks = (waves + WPB - 1) / WPB;
            scan_dma_kernel<<<blocks, 64 * WPB, 0, stream>>>(
                shuffled_ind, g, l, pt_inv, pooled, N);
        }
        {
            const int blocks = (M + 2 * WPB - 1) / (2 * WPB);
            gemm_kernel<<<blocks, 64 * WPB, 0, stream>>>(pooled, W, b, out, M);
        }
    } else {
        int* starts = (int*)d_ws;
        {
            const int blocks = (M + 1 + 255) / 256;
            seg_starts_kernel<<<blocks, 256, 0, stream>>>(pt_inv, N, starts, M);
        }
        {
            const int blocks = (M + WPB - 1) / WPB;
            pool_gemm_kernel<<<blocks, 64 * WPB, 0, stream>>>(
                shuffled_ind, g, l, starts, W, b, out, M);
        }
    }
}